// Round 1
// baseline (317.095 us; speedup 1.0000x reference)
//
#include <hip/hip_runtime.h>
#include <hip/hip_bf16.h>

#define N_TOK 2048
#define B_SZ  8
#define E_DIM 256
#define H_DIM 512

typedef __attribute__((ext_vector_type(8))) short bf16x8;
typedef __attribute__((ext_vector_type(4))) float f32x4;

__device__ __forceinline__ unsigned short f2bf(float f) {
    union { float f; unsigned u; } v; v.f = f;
    unsigned r = v.u + 0x7FFF + ((v.u >> 16) & 1);   // RNE
    return (unsigned short)(r >> 16);
}
__device__ __forceinline__ float bf2f(unsigned short b) {
    union { unsigned u; float f; } v; v.u = ((unsigned)b) << 16;
    return v.f;
}

// ---------------- Kernel 1: row-normalize x -> Xn bf16, layout (B, N, E) ----
__global__ void norm_kernel(const float* __restrict__ x,
                            unsigned short* __restrict__ Xn) {
    int r = blockIdx.x;            // r = i*B + b  (memory order of x)
    int i = r >> 3, b = r & 7;     // B_SZ == 8
    int t = threadIdx.x;           // 256 threads == E_DIM
    float v = x[(size_t)r * E_DIM + t];
    float s = v * v;
    #pragma unroll
    for (int o = 32; o > 0; o >>= 1) s += __shfl_xor(s, o);
    __shared__ float red[4];
    int lane = t & 63, w = t >> 6;
    if (lane == 0) red[w] = s;
    __syncthreads();
    float tot = red[0] + red[1] + red[2] + red[3];
    float rn = 1.0f / sqrtf(tot);
    Xn[((size_t)b * N_TOK + i) * E_DIM + t] = f2bf(v * rn);
}

// ---------------- Kernel 2: transpose h (N,B,H) f32 -> Vt (B,H,N) bf16 -----
__global__ void transpose_kernel(const float* __restrict__ h,
                                 unsigned short* __restrict__ Vt) {
    __shared__ float tile[32][33];
    int j0 = blockIdx.x * 32, h0 = blockIdx.y * 32, b = blockIdx.z;
    int tx = threadIdx.x & 31, ty = threadIdx.x >> 5;   // 32 x 8 threads
    #pragma unroll
    for (int it = 0; it < 4; it++) {
        int j = j0 + ty + it * 8;
        tile[ty + it * 8][tx] = h[((size_t)j * B_SZ + b) * H_DIM + h0 + tx];
    }
    __syncthreads();
    #pragma unroll
    for (int it = 0; it < 4; it++) {
        int hh = h0 + ty + it * 8;
        Vt[((size_t)b * H_DIM + hh) * N_TOK + j0 + tx] = f2bf(tile[tx][ty + it * 8]);
    }
}

// ---------------- Kernel 3: fused flash attention ---------------------------
// grid (N/32, B), 256 threads (4 waves). Q-tile = 32 rows.
// Wave w: QK^T sub-tile (mg = w>>1, ng = w&1); PV h-chunk [128w, 128w+128).
__launch_bounds__(256, 2)
__global__ void flash_kernel(const unsigned short* __restrict__ Xn,
                             const unsigned short* __restrict__ Vt,
                             float* __restrict__ out,
                             float* __restrict__ sumsq) {
    constexpr int KP = 264;   // K_lds row stride (shorts): 256 + 8 pad
    constexpr int SP = 36;    // S_lds row stride (floats)
    constexpr int PP = 40;    // P_lds row stride (shorts)
    __shared__ __attribute__((aligned(16))) unsigned short K_lds[32 * KP];
    __shared__ __attribute__((aligned(16))) float          S_lds[32 * SP];
    __shared__ __attribute__((aligned(16))) unsigned short P_lds[32 * PP];
    __shared__ float m_row[32], l_row[32], a_row[32];

    int q0 = blockIdx.x * 32;
    int b  = blockIdx.y;
    int t = threadIdx.x;
    int w = t >> 6, lane = t & 63;
    int quad = lane >> 4, nm = lane & 15;
    int mg = w >> 1, ng = w & 1;

    if (t < 32) { m_row[t] = -INFINITY; l_row[t] = 0.0f; }

    // Q fragments for this wave's row-group mg, register-resident
    const unsigned short* Qrow =
        Xn + ((size_t)b * N_TOK + q0 + mg * 16 + nm) * E_DIM;
    bf16x8 qf[8];
    #pragma unroll
    for (int ec = 0; ec < 8; ec++)
        qf[ec] = *(const bf16x8*)(Qrow + ec * 32 + quad * 8);

    f32x4 O[2][8];
    #pragma unroll
    for (int i = 0; i < 2; i++)
        #pragma unroll
        for (int j = 0; j < 8; j++)
            O[i][j] = (f32x4){0.f, 0.f, 0.f, 0.f};

    int sr = t >> 3;          // softmax row 0..31 (8 lanes per row, same wave)
    int sc = (t & 7) * 4;     // softmax col base

    const unsigned short* Kbase = Xn + (size_t)b * N_TOK * E_DIM;
    const unsigned short* Vbase =
        Vt + ((size_t)b * H_DIM + (size_t)w * 128) * N_TOK;

    for (int j0 = 0; j0 < N_TOK; j0 += 32) {
        // ---- stage K tile (32 x 256 bf16) ----
        {
            int r = t >> 3, c = (t & 7) * 32;
            const unsigned short* src = Kbase + (size_t)(j0 + r) * E_DIM + c;
            unsigned short* dst = K_lds + r * KP + c;
            #pragma unroll
            for (int k = 0; k < 4; k++)
                *(bf16x8*)(dst + k * 8) = *(const bf16x8*)(src + k * 8);
        }
        __syncthreads();

        // ---- QK^T: one 16x16 tile per wave ----
        f32x4 s_acc = (f32x4){0.f, 0.f, 0.f, 0.f};
        const unsigned short* Krow = K_lds + (ng * 16 + nm) * KP;
        #pragma unroll
        for (int ec = 0; ec < 8; ec++) {
            bf16x8 kf = *(const bf16x8*)(Krow + ec * 32 + quad * 8);
            s_acc = __builtin_amdgcn_mfma_f32_16x16x32_bf16(qf[ec], kf, s_acc, 0, 0, 0);
        }
        #pragma unroll
        for (int r = 0; r < 4; r++)
            S_lds[(mg * 16 + quad * 4 + r) * SP + ng * 16 + nm] = s_acc[r];
        __syncthreads();

        // ---- online softmax (row sr, 8 lanes x 4 cols) ----
        {
            float4 sv = *(const float4*)(S_lds + sr * SP + sc);
            float mx = fmaxf(fmaxf(sv.x, sv.y), fmaxf(sv.z, sv.w));
            #pragma unroll
            for (int o = 1; o < 8; o <<= 1) mx = fmaxf(mx, __shfl_xor(mx, o));
            float m_old = m_row[sr];
            float m_new = fmaxf(m_old, mx);
            unsigned short pb0 = f2bf(__expf(sv.x - m_new));
            unsigned short pb1 = f2bf(__expf(sv.y - m_new));
            unsigned short pb2 = f2bf(__expf(sv.z - m_new));
            unsigned short pb3 = f2bf(__expf(sv.w - m_new));
            float psum = bf2f(pb0) + bf2f(pb1) + bf2f(pb2) + bf2f(pb3);
            #pragma unroll
            for (int o = 1; o < 8; o <<= 1) psum += __shfl_xor(psum, o);
            float alpha = __expf(m_old - m_new);
            if ((t & 7) == 0) {
                m_row[sr] = m_new;
                l_row[sr] = l_row[sr] * alpha + psum;
                a_row[sr] = alpha;
            }
            *(ushort4*)(P_lds + sr * PP + sc) = make_ushort4(pb0, pb1, pb2, pb3);
        }
        __syncthreads();

        // ---- rescale O, then PV ----
        float al[2][4];
        #pragma unroll
        for (int i = 0; i < 2; i++)
            #pragma unroll
            for (int r = 0; r < 4; r++)
                al[i][r] = a_row[i * 16 + quad * 4 + r];
        #pragma unroll
        for (int i = 0; i < 2; i++)
            #pragma unroll
            for (int j = 0; j < 8; j++)
                #pragma unroll
                for (int r = 0; r < 4; r++)
                    O[i][j][r] *= al[i][r];

        bf16x8 pf0 = *(const bf16x8*)(P_lds + (0  + nm) * PP + quad * 8);
        bf16x8 pf1 = *(const bf16x8*)(P_lds + (16 + nm) * PP + quad * 8);
        #pragma unroll
        for (int hg = 0; hg < 8; hg++) {
            const unsigned short* vp =
                Vbase + (size_t)(hg * 16 + nm) * N_TOK + j0 + quad * 8;
            bf16x8 vf = *(const bf16x8*)vp;
            O[0][hg] = __builtin_amdgcn_mfma_f32_16x16x32_bf16(pf0, vf, O[0][hg], 0, 0, 0);
            O[1][hg] = __builtin_amdgcn_mfma_f32_16x16x32_bf16(pf1, vf, O[1][hg], 0, 0, 0);
        }
    }

    // ---- epilogue: divide by l, write g, accumulate sum of squares ----
    float linv[2][4];
    #pragma unroll
    for (int i = 0; i < 2; i++)
        #pragma unroll
        for (int r = 0; r < 4; r++)
            linv[i][r] = 1.0f / l_row[i * 16 + quad * 4 + r];

    float ss = 0.0f;
    #pragma unroll
    for (int i = 0; i < 2; i++) {
        #pragma unroll
        for (int hg = 0; hg < 8; hg++) {
            int hcol = w * 128 + hg * 16 + nm;
            #pragma unroll
            for (int r = 0; r < 4; r++) {
                float val = O[i][hg][r] * linv[i][r];
                int row = q0 + i * 16 + quad * 4 + r;
                out[((size_t)row * B_SZ + b) * H_DIM + hcol] = val;
                ss += val * val;
            }
        }
    }
    #pragma unroll
    for (int o = 1; o < 64; o <<= 1) ss += __shfl_xor(ss, o);
    if (lane == 0) atomicAdd(sumsq, ss);
}

// ---------------- Kernel 4: global-norm rescale -----------------------------
__global__ void scale_kernel(float* __restrict__ out,
                             const float* __restrict__ sumsq) {
    size_t idx = ((size_t)blockIdx.x * blockDim.x + threadIdx.x) * 4;
    float rs = 1.0f / sqrtf(*sumsq);
    float4 v = *(float4*)(out + idx);
    v.x *= rs; v.y *= rs; v.z *= rs; v.w *= rs;
    *(float4*)(out + idx) = v;
}

extern "C" void kernel_launch(void* const* d_in, const int* in_sizes, int n_in,
                              void* d_out, int out_size, void* d_ws, size_t ws_size,
                              hipStream_t stream) {
    const float* x = (const float*)d_in[0];
    const float* h = (const float*)d_in[1];
    float* out = (float*)d_out;

    unsigned short* Xn = (unsigned short*)d_ws;                       // 8 MB
    unsigned short* Vt = Xn + (size_t)B_SZ * N_TOK * E_DIM;           // 16 MB
    float* sumsq = (float*)(Vt + (size_t)B_SZ * H_DIM * N_TOK);      // 4 B

    hipMemsetAsync(sumsq, 0, sizeof(float), stream);
    norm_kernel<<<N_TOK * B_SZ, 256, 0, stream>>>(x, Xn);
    transpose_kernel<<<dim3(N_TOK / 32, H_DIM / 32, B_SZ), 256, 0, stream>>>(h, Vt);
    flash_kernel<<<dim3(N_TOK / 32, B_SZ), 256, 0, stream>>>(Xn, Vt, out, sumsq);
    scale_kernel<<<out_size / (4 * 256), 256, 0, stream>>>(out, sumsq);
}